// Round 16
// baseline (301.104 us; speedup 1.0000x reference)
//
#include <hip/hip_runtime.h>
#include <hip/hip_bf16.h>
#include <cstdint>
#include <cstddef>

typedef unsigned short bf16t;
typedef __attribute__((ext_vector_type(8))) short bf16x8;  // 8 bf16 (4 VGPRs)
typedef __attribute__((ext_vector_type(4))) float f32x4;   // MFMA C/D

// ---------- helpers ----------
__device__ __forceinline__ unsigned short f2bf(float f) {
    unsigned u = __float_as_uint(f);
    u += 0x7fffu + ((u >> 16) & 1u);   // RNE
    return (unsigned short)(u >> 16);
}
__device__ __forceinline__ float bf2f(unsigned short h) {
    return __uint_as_float(((unsigned)h) << 16);
}
__device__ __forceinline__ float bflo(unsigned u) { return __uint_as_float(u << 16); }
__device__ __forceinline__ float bfhi(unsigned u) { return __uint_as_float(u & 0xffff0000u); }
// packed f32x2 -> bf16x2 via v_cvt_pk_bf16_f32
__device__ __forceinline__ unsigned pk2(float a, float b) {
    __hip_bfloat162 h = __float22bfloat162_rn(make_float2(a, b));
    return *(unsigned*)&h;
}
__device__ __forceinline__ bf16x8 mk8(unsigned a, unsigned b, unsigned c, unsigned d) {
    union { uint4 u; bf16x8 v; } cv; cv.u = make_uint4(a, b, c, d); return cv.v;
}
// native 2^x (v_exp_f32, no pre-multiply) — Q is pre-scaled by log2e in conv
__device__ __forceinline__ float fexp2(float x) {
#if __has_builtin(__builtin_amdgcn_exp2f)
    return __builtin_amdgcn_exp2f(x);
#else
    return exp2f(x);
#endif
}

// order-preserving float<->uint encoding for atomicMax
__device__ __forceinline__ unsigned fenc(float f) {
    unsigned u = __float_as_uint(f);
    return (u & 0x80000000u) ? ~u : (u | 0x80000000u);
}
__device__ __forceinline__ float fdec(unsigned u) {
    return __uint_as_float((u & 0x80000000u) ? (u ^ 0x80000000u) : ~u);
}

#define HW 65536
#define LOG2E 1.44269504088896f

// ---------- K1: MFMA 1x1 conv: Out[80,HW] = W[80,64] * X[64,HW], X/W cast bf16 ----------
// Q rows (o<8) are pre-scaled by log2e so rowcc can use raw v_exp_f32 (2^x).
struct ConvArgs {
    const float* x[2];
    const float* wq[2]; const float* bq[2];
    const float* wk[2]; const float* bk[2];
    const float* wv[2]; const float* bv[2];
    bf16t* q[2]; bf16t* k[2]; bf16t* v[2];
    unsigned* zeroR;    // 1536 u32: accum (1280 f32) + accmax (256 u32)
};

__global__ __launch_bounds__(256) void conv_qkv(ConvArgs A)
{
    __shared__ __align__(16) bf16t Xlds[256 * 68];   // [px][ch], stride 68

    const int t = threadIdx.x;
    const int z = blockIdx.z;
    const int s = z >> 1, b = z & 1;
    if (z == 0 && blockIdx.x == 0) {
#pragma unroll
        for (int i = 0; i < 6; i++) A.zeroR[t + i * 256] = 0u;
    }
    const int lane = t & 63, wv = t >> 6, quad = lane >> 4, l16 = lane & 15;
    const int px0 = blockIdx.x * 256;

    // --- load X column (64 ch) for px = px0 + t; pack bf16; stage transposed ---
    const float* xp = A.x[s] + (size_t)b * 64 * HW + px0 + t;
    {
        unsigned xw[32];
#pragma unroll
        for (int c = 0; c < 32; c++)
            xw[c] = pk2(xp[(size_t)(2 * c) * HW], xp[(size_t)(2 * c + 1) * HW]);
#pragma unroll
        for (int g = 0; g < 16; g++)
            *(uint2*)&Xlds[t * 68 + g * 4] = make_uint2(xw[2 * g], xw[2 * g + 1]);
    }

    // --- B-frags (W) + bias + output row pointers: o = ot*16 + l16 ---
    bf16x8 bfr[5][2];
    float bo[5];
    bf16t* obase[5];
#pragma unroll
    for (int ot = 0; ot < 5; ot++) {
        const int o = ot * 16 + l16;
        const float* wrow;
        float qs = 1.0f;
        if (o < 8)       { wrow = A.wq[s] + o * 64;        bo[ot] = A.bq[s][o] * LOG2E; qs = LOG2E;
                           obase[ot] = A.q[s] + (size_t)(b * 8 + o) * HW; }
        else if (o < 16) { wrow = A.wk[s] + (o - 8) * 64;  bo[ot] = A.bk[s][o - 8];
                           obase[ot] = A.k[s] + (size_t)(b * 8 + o - 8) * HW; }
        else             { wrow = A.wv[s] + (o - 16) * 64; bo[ot] = A.bv[s][o - 16];
                           obase[ot] = A.v[s] + (size_t)(b * 64 + o - 16) * HW; }
#pragma unroll
        for (int ks = 0; ks < 2; ks++) {
            const float* wp = wrow + ks * 32 + quad * 8;
            bfr[ot][ks] = mk8(pk2(wp[0] * qs, wp[1] * qs), pk2(wp[2] * qs, wp[3] * qs),
                              pk2(wp[4] * qs, wp[5] * qs), pk2(wp[6] * qs, wp[7] * qs));
        }
    }

    __syncthreads();

    // --- A-frags (X^T): wave's px band = wv*64 .. +63, 4 m-tiles ---
    bf16x8 afr[4][2];
#pragma unroll
    for (int i = 0; i < 4; i++)
#pragma unroll
        for (int ks = 0; ks < 2; ks++) {
            const int base = (wv * 64 + i * 16 + l16) * 68 + ks * 32 + quad * 8;
            const uint2 lo = *(const uint2*)&Xlds[base];
            const uint2 hi = *(const uint2*)&Xlds[base + 4];
            afr[i][ks] = mk8(lo.x, lo.y, hi.x, hi.y);
        }

    const f32x4 z4 = {0.f, 0.f, 0.f, 0.f};
    f32x4 acc[4][5];
#pragma unroll
    for (int i = 0; i < 4; i++)
#pragma unroll
        for (int ot = 0; ot < 5; ot++) acc[i][ot] = z4;

#pragma unroll
    for (int ks = 0; ks < 2; ks++)
#pragma unroll
        for (int i = 0; i < 4; i++)
#pragma unroll
            for (int ot = 0; ot < 5; ot++)
                acc[i][ot] = __builtin_amdgcn_mfma_f32_16x16x32_bf16(afr[i][ks], bfr[ot][ks], acc[i][ot], 0, 0, 0);

    // --- epilogue: C rows = px (quad*4+r), cols = o (l16); direct 8B stores ---
#pragma unroll
    for (int i = 0; i < 4; i++) {
        const int px = px0 + wv * 64 + i * 16 + quad * 4;
#pragma unroll
        for (int ot = 0; ot < 5; ot++) {
            uint2 u;
            u.x = pk2(acc[i][ot][0] + bo[ot], acc[i][ot][1] + bo[ot]);
            u.y = pk2(acc[i][ot][2] + bo[ot], acc[i][ot][3] + bo[ot]);
            *(uint2*)&obase[ot][px] = u;
        }
    }
}

// ---------- bf16 transpose, widened: uint (2 elems) per lane both directions ----------
__global__ __launch_bounds__(256) void transpose16(const bf16t* __restrict__ in, bf16t* __restrict__ out)
{
    __shared__ unsigned tile[64][33];   // [row][col-pair]: lo16 = col 2c, hi16 = col 2c+1
    const size_t zo = (size_t)blockIdx.z * HW;
    const int i0 = blockIdx.y * 64, j0 = blockIdx.x * 64;
    const int cp = threadIdx.x & 31;       // col-pair 0..31
    const int r8 = threadIdx.x >> 5;       // 0..7
#pragma unroll
    for (int rr = 0; rr < 8; rr++) {
        const int row = rr * 8 + r8;
        tile[row][cp] = *(const unsigned*)&in[zo + (size_t)(i0 + row) * 256 + j0 + cp * 2];
    }
    __syncthreads();
    const int ip = threadIdx.x & 31;       // output i-pair
    const int j8 = threadIdx.x >> 5;
#pragma unroll
    for (int jj = 0; jj < 8; jj++) {
        const int j = jj * 8 + j8;
        const unsigned a = tile[2 * ip][j >> 1];
        const unsigned b = tile[2 * ip + 1][j >> 1];
        const unsigned lo = (j & 1) ? (a >> 16) : (a & 0xffffu);
        const unsigned hi = (j & 1) ? (b >> 16) : (b & 0xffffu);
        *(unsigned*)&out[zo + (size_t)(j0 + j) * 256 + i0 + ip * 2] = lo | (hi << 16);
    }
}

// ---------- K2: criss-cross rows (verified r13: 47.9 us) ----------
struct RowccArgs {
    const bf16t* q[4]; const bf16t* k[4]; const bf16t* v[4];
    bf16t* o[4]; float* so[4];
};

__global__ __launch_bounds__(256, 3) void rowcc_mfma(RowccArgs P)
{
    __shared__ __align__(16) bf16t vs[64 * 264];     // V [c][j]; epilogue overlays
    __shared__ __align__(16) bf16t klds[256 * 8];    // K transposed [j][ch]

    const int t = threadIdx.x;
    const int r = blockIdx.x, b = blockIdx.y, z = blockIdx.z;
    const bool mask = (z < 2);
    const int lane = t & 63, wv = t >> 6, quad = lane >> 4, l16 = lane & 15;
    const int wband = wv * 64;
    const int jperm = 8 * (l16 >> 2) + (l16 & 3);   // score-row m=l16 -> j offset

    const bf16t* qp = P.q[z];
    const bf16t* kp = P.k[z];
    const bf16t* vp = P.v[z];
    const size_t rowb = (size_t)b * 8 * HW + (size_t)r * 256;

    // --- stage V as [c][j] (row stride 264) ---
    const size_t vb = (size_t)b * 64 * HW + (size_t)r * 256;
#pragma unroll
    for (int i = 0; i < 8; i++) {
        const int qd = i * 256 + t;
        const int c = qd >> 5, jc = (qd & 31) * 8;
        *(uint4*)&vs[c * 264 + jc] = *(const uint4*)&vp[vb + (size_t)c * HW + jc];
    }

    // --- stage K transposed: thread t handles j=t (8 coalesced ch loads + 1 b128 write) ---
    {
        bf16t kv[8];
#pragma unroll
        for (int ch = 0; ch < 8; ch++)
            kv[ch] = kp[rowb + (size_t)ch * HW + t];
        *(uint4*)&klds[t * 8] = *(const uint4*)kv;
    }

    // --- Q B-frags from global (quad0 lanes only; quads 1-3 are K-zero-pad) ---
    const bf16x8 zfr = {0, 0, 0, 0, 0, 0, 0, 0};
    bf16x8 qfr[4] = {zfr, zfr, zfr, zfr};
    if (quad == 0) {
#pragma unroll
        for (int wt = 0; wt < 4; wt++) {
            const int w_g = wband + wt * 16 + l16;
#pragma unroll
            for (int ch = 0; ch < 8; ch++)
                qfr[wt][ch] = (short)qp[rowb + (size_t)ch * HW + w_g];
        }
    }

    const f32x4 z4 = {0.f, 0.f, 0.f, 0.f};
    f32x4 acc[4][4];
#pragma unroll
    for (int i = 0; i < 4; i++)
#pragma unroll
        for (int j = 0; j < 4; j++) acc[i][j] = z4;
    float s_t[4] = {0.f, 0.f, 0.f, 0.f};

    __syncthreads();

    // K A-frag prefetch for jt=0, from LDS
    bf16x8 kcur[2] = {zfr, zfr};
    if (quad == 0) {
#pragma unroll
        for (int jtile = 0; jtile < 2; jtile++)
            kcur[jtile] = *(const bf16x8*)&klds[(jtile * 4 + jperm) * 8];
    }

    for (int jt = 0; jt < 8; jt++) {
        const int j0 = jt * 32;

        // V B-frags for this jt (independent of scores; issue early)
        bf16x8 bfr[4];
#pragma unroll
        for (int ct = 0; ct < 4; ct++)
            bfr[ct] = *(const bf16x8*)&vs[(ct * 16 + l16) * 264 + j0 + quad * 8];

        // prefetch next jt's K frags from LDS (cheap, hidden under MFMA/exp)
        bf16x8 knext[2] = {zfr, zfr};
        if (jt < 7 && quad == 0) {
            const int jn = (jt + 1) * 32;
#pragma unroll
            for (int jtile = 0; jtile < 2; jtile++)
                knext[jtile] = *(const bf16x8*)&klds[(jn + jtile * 4 + jperm) * 8];
        }

        const bool dodiag = mask && ((jt >> 1) == wv);

#pragma unroll
        for (int wt = 0; wt < 4; wt++) {
            f32x4 e0 = __builtin_amdgcn_mfma_f32_16x16x32_bf16(kcur[0], qfr[wt], z4, 0, 0, 0);
            f32x4 e1 = __builtin_amdgcn_mfma_f32_16x16x32_bf16(kcur[1], qfr[wt], z4, 0, 0, 0);

            if (dodiag) {
                const int w_g = wband + wt * 16 + l16;
                const int jb = j0 + 8 * quad;
#pragma unroll
                for (int rr = 0; rr < 4; rr++) {
                    if (jb + rr == w_g)     e0[rr] = -3.0e38f;
                    if (jb + 4 + rr == w_g) e1[rr] = -3.0e38f;
                }
            }

            // p = 2^e (Q pre-scaled by log2e); accumulate denominator;
            // pack PV A-frag in registers
            float p[8];
#pragma unroll
            for (int rr = 0; rr < 4; rr++) {
                p[rr]     = fexp2(e0[rr]);
                p[4 + rr] = fexp2(e1[rr]);
            }
            s_t[wt] += ((p[0] + p[1]) + (p[2] + p[3])) + ((p[4] + p[5]) + (p[6] + p[7]));
            const bf16x8 pa = mk8(pk2(p[0], p[1]), pk2(p[2], p[3]),
                                  pk2(p[4], p[5]), pk2(p[6], p[7]));

            // PV: A = P (w x j), B = V (j x c)
#pragma unroll
            for (int ct = 0; ct < 4; ct++)
                acc[wt][ct] = __builtin_amdgcn_mfma_f32_16x16x32_bf16(pa, bfr[ct], acc[wt][ct], 0, 0, 0);
        }

        kcur[0] = knext[0]; kcur[1] = knext[1];
    }

    // denominator: reduce across quads (each quad holds a disjoint j-subset)
#pragma unroll
    for (int wt = 0; wt < 4; wt++) {
        float s = s_t[wt];
        s += __shfl_xor(s, 16, 64);
        s += __shfl_xor(s, 32, 64);
        s_t[wt] = s;
    }
    if (quad == 0) {
#pragma unroll
        for (int wt = 0; wt < 4; wt++) {
            const int w_g = wband + wt * 16 + l16;
            if (mask)  // column pass: pixel (h=w_g, w=r) in row-frame
                P.so[z][(size_t)b * HW + w_g * 256 + r] = s_t[wt];
            else
                P.so[z][(size_t)b * HW + r * 256 + w_g] = s_t[wt];
        }
    }

    // epilogue: C-layout -> LDS [c][w] -> coalesced global [c][w]
    __syncthreads();
    bf16t* o_lds = vs;
#pragma unroll
    for (int wt = 0; wt < 4; wt++) {
        const int w0 = wband + wt * 16 + quad * 4;
#pragma unroll
        for (int ct = 0; ct < 4; ct++) {
            const int c = ct * 16 + l16;
            uint2 u;
            u.x = pk2(acc[wt][ct][0], acc[wt][ct][1]);
            u.y = pk2(acc[wt][ct][2], acc[wt][ct][3]);
            *(uint2*)&o_lds[c * 264 + w0] = u;
        }
    }
    __syncthreads();
    bf16t* ob = P.o[z] + (size_t)b * 64 * HW + (size_t)r * 256;
#pragma unroll
    for (int i = 0; i < 8; i++) {
        const int qd = i * 256 + t;
        const int c = qd >> 5, w8 = (qd & 31) * 8;
        *(uint4*)&ob[(size_t)c * HW + w8] = *(const uint4*)&o_lds[c * 264 + w8];
    }
}

// ---------- K4: combine, WIDE lanes: block = 16h x 256w, lane owns 4 w ----------
// All global accesses >=8B/lane: sH/sW/x float4, oW/s1/s2 uint2, even-out
// float4, oHT stage 2x uint4 (16 contiguous h per w). Grid (16,64,2) = 2048
// blocks (round-6 lesson: keep parallelism).
__global__ __launch_bounds__(256) void combine_reduce(
    const bf16t* __restrict__ oH1T, const bf16t* __restrict__ oW1,
    const bf16t* __restrict__ oH2T, const bf16t* __restrict__ oW2,
    const float* __restrict__ sH1, const float* __restrict__ sW1,
    const float* __restrict__ sH2, const float* __restrict__ sW2,
    const float* __restrict__ x1, const float* __restrict__ x2,
    const float* __restrict__ gamma1, const float* __restrict__ gamma2,
    bf16t* __restrict__ s1, bf16t* __restrict__ s2,
    float* __restrict__ out1, float* __restrict__ out2,
    float* __restrict__ accum, unsigned* __restrict__ accmax)
{
    __shared__ bf16t oth1[16][264];   // [h_local][w], transposed stage
    __shared__ bf16t oth2[16][264];

    const int t = threadIdx.x;
    const int hblk = blockIdx.x, c = blockIdx.y, b = blockIdx.z;
    const float g1v = gamma1[0], g2v = gamma2[0];
    const size_t cb = ((size_t)(b * 64 + c)) * HW;
    const size_t pb = (size_t)b * HW;
    const bool codd = (c & 1) != 0;
    const int h0 = hblk * 16;

    // --- stage: thread t owns w=t; oHT[c][w*256 + h0 + 0..15] = 32B = 2 uint4 ---
    {
        const size_t g = cb + (size_t)t * 256 + h0;
        const uint4 a1 = *(const uint4*)&oH1T[g];
        const uint4 b1 = *(const uint4*)&oH1T[g + 8];
        const uint4 a2 = *(const uint4*)&oH2T[g];
        const uint4 b2 = *(const uint4*)&oH2T[g + 8];
        const unsigned w1u[8] = {a1.x, a1.y, a1.z, a1.w, b1.x, b1.y, b1.z, b1.w};
        const unsigned w2u[8] = {a2.x, a2.y, a2.z, a2.w, b2.x, b2.y, b2.z, b2.w};
#pragma unroll
        for (int i = 0; i < 8; i++) {
            oth1[2 * i + 0][t] = (bf16t)(w1u[i] & 0xffffu);
            oth1[2 * i + 1][t] = (bf16t)(w1u[i] >> 16);
            oth2[2 * i + 0][t] = (bf16t)(w2u[i] & 0xffffu);
            oth2[2 * i + 1][t] = (bf16t)(w2u[i] >> 16);
        }
    }
    __syncthreads();

    const int l = t & 63, wv = t >> 6;
    const int w4 = l * 4;                 // lane's 4 w columns

    float pS1 = 0, pSS1 = 0, pSX1 = 0, pX1 = 0, pXX1 = 0, pM1 = -3e38f;
    float pS2 = 0, pSS2 = 0, pSX2 = 0, pX2 = 0, pXX2 = 0, pM2 = -3e38f;

    // --- process: wave wv handles h_local = wv*4 + k, k=0..3; lane covers w4..w4+3 ---
#pragma unroll
    for (int k = 0; k < 4; k++) {
        const int hl = wv * 4 + k;
        const int pidx = (h0 + hl) * 256 + w4;
        const float4 sh1 = *(const float4*)&sH1[pb + pidx];
        const float4 sw1 = *(const float4*)&sW1[pb + pidx];
        const float4 sh2 = *(const float4*)&sH2[pb + pidx];
        const float4 sw2 = *(const float4*)&sW2[pb + pidx];
        const uint2 ow1 = *(const uint2*)&oW1[cb + pidx];
        const uint2 ow2 = *(const uint2*)&oW2[cb + pidx];
        const uint2 oh1 = *(const uint2*)&oth1[hl][w4];
        const uint2 oh2 = *(const uint2*)&oth2[hl][w4];
        const float4 x1v = *(const float4*)&x1[cb + pidx];
        const float4 x2v = *(const float4*)&x2[cb + pidx];

        const float i1[4] = {1.f / (sh1.x + sw1.x), 1.f / (sh1.y + sw1.y),
                             1.f / (sh1.z + sw1.z), 1.f / (sh1.w + sw1.w)};
        const float i2[4] = {1.f / (sh2.x + sw2.x), 1.f / (sh2.y + sw2.y),
                             1.f / (sh2.z + sw2.z), 1.f / (sh2.w + sw2.w)};
        const float a1v[4] = {(bflo(oh1.x) + bflo(ow1.x)) * i1[0], (bfhi(oh1.x) + bfhi(ow1.x)) * i1[1],
                              (bflo(oh1.y) + bflo(ow1.y)) * i1[2], (bfhi(oh1.y) + bfhi(ow1.y)) * i1[3]};
        const float a2v[4] = {(bflo(oh2.x) + bflo(ow2.x)) * i2[0], (bfhi(oh2.x) + bfhi(ow2.x)) * i2[1],
                              (bflo(oh2.y) + bflo(ow2.y)) * i2[2], (bfhi(oh2.y) + bfhi(ow2.y)) * i2[3]};
        const float xa[4] = {x1v.x, x1v.y, x1v.z, x1v.w};
        const float xb[4] = {x2v.x, x2v.y, x2v.z, x2v.w};
        float s1v[4], s2v[4];
#pragma unroll
        for (int j = 0; j < 4; j++) {
            s1v[j] = g2v * a2v[j] + xb[j] + xa[j];
            s2v[j] = g1v * a1v[j] + xa[j] + xb[j];
            pS1 += s1v[j]; pSS1 += s1v[j] * s1v[j]; pSX1 += s1v[j] * xa[j];
            pX1 += xa[j];  pXX1 += xa[j] * xa[j];   pM1 = fmaxf(pM1, s1v[j]);
            pS2 += s2v[j]; pSS2 += s2v[j] * s2v[j]; pSX2 += s2v[j] * xb[j];
            pX2 += xb[j];  pXX2 += xb[j] * xb[j];   pM2 = fmaxf(pM2, s2v[j]);
        }
        if (codd) {
            uint2 u1, u2;
            u1.x = pk2(s1v[0], s1v[1]); u1.y = pk2(s1v[2], s1v[3]);
            u2.x = pk2(s2v[0], s2v[1]); u2.y = pk2(s2v[2], s2v[3]);
            *(uint2*)&s1[cb + pidx] = u1;
            *(uint2*)&s2[cb + pidx] = u2;
        } else {
            *(float4*)&out1[cb + pidx] = x1v;   // even c: passthrough, final value
            *(float4*)&out2[cb + pidx] = x2v;
        }
    }

    __shared__ float wred[12][4];
    float vals[12] = {pS1, pSS1, pSX1, pX1, pXX1, pM1, pS2, pSS2, pSX2, pX2, pXX2, pM2};
#pragma unroll
    for (int iv = 0; iv < 12; iv++) {
        float v = vals[iv];
        const bool isMax = (iv == 5 || iv == 11);
#pragma unroll
        for (int off = 32; off > 0; off >>= 1) {
            const float o = __shfl_down(v, off, 64);
            v = isMax ? fmaxf(v, o) : (v + o);
        }
        if (l == 0) wred[iv][wv] = v;
    }
    __syncthreads();
    if (t < 12) {
        const bool isMax = (t == 5 || t == 11);
        float v = wred[t][0];
        for (int i = 1; i < 4; i++) v = isMax ? fmaxf(v, wred[t][i]) : (v + wred[t][i]);
        const int stream = (t >= 6) ? 1 : 0;
        const int kk = t - stream * 6;
        if (kk == 5) atomicMax(&accmax[(stream * 2 + b) * 64 + c], fenc(v));
        else atomicAdd(&accum[((stream * 2 + b) * 64 + c) * 5 + kk], v);
    }
}

// ---------- K5: gates (shareca MLP) + analytic BN coefficients ----------
__global__ __launch_bounds__(256) void gates_bn(
    const float* __restrict__ accum, const unsigned* __restrict__ accmax,
    const float* __restrict__ sc1_w1, const float* __restrict__ sc1_b1,
    const float* __restrict__ sc1_w2, const float* __restrict__ sc1_b2,
    const float* __restrict__ sc2_w1, const float* __restrict__ sc2_b1,
    const float* __restrict__ sc2_w2, const float* __restrict__ sc2_b2,
    const float* __restrict__ bn1_scale, const float* __restrict__ bn1_bias,
    const float* __restrict__ bn2_scale, const float* __restrict__ bn2_bias,
    float* __restrict__ gates, float* __restrict__ AB)
{
    const int t = threadIdx.x;
    const int stream = t >> 7, b = (t >> 6) & 1, c = t & 63;
    __shared__ float meanS[256], maxS[256], e1S[256], e2S[256];

    const float S = accum[t * 5 + 0], SS = accum[t * 5 + 1], SX = accum[t * 5 + 2];
    const float X = accum[t * 5 + 3], XX = accum[t * 5 + 4];
    meanS[t] = S * (1.f / 65536.f);
    maxS[t] = fdec(accmax[t]);
    __syncthreads();

    const float* w1 = stream ? sc2_w1 : sc1_w1;
    const float* b1 = stream ? sc2_b1 : sc1_b1;
    const float* w2 = stream ? sc2_w2 : sc1_w2;
    const float* b2 = stream ? sc2_b2 : sc1_b2;
    float om = b2[c], ox = b2[c];
    const int base = stream * 128 + b * 64;
#pragma unroll
    for (int r = 0; r < 4; r++) {
        float hm = b1[r], hx = b1[r];
        for (int cc = 0; cc < 64; cc++) {
            hm += w1[r * 64 + cc] * meanS[base + cc];
            hx += w1[r * 64 + cc] * maxS[base + cc];
        }
        hm = fmaxf(hm, 0.f); hx = fmaxf(hx, 0.f);
        om += w2[c * 4 + r] * hm;
        ox += w2[c * 4 + r] * hx;
    }
    const float gate = 1.f / (1.f + __expf(-(om + ox)));
    gates[t] = gate;
    e1S[t] = gate * S + X;
    e2S[t] = gate * gate * SS + 2.f * gate * SX + XX;
    __syncthreads();
    if (b == 0) {
        const float sumY = e1S[t] + e1S[t + 64];
        const float sumY2 = e2S[t] + e2S[t + 64];
        const float meanY = sumY * (1.f / 131072.f);
        const float varY = sumY2 * (1.f / 131072.f) - meanY * meanY;
        const float sc = stream ? bn2_scale[c] : bn1_scale[c];
        const float bi = stream ? bn2_bias[c] : bn1_bias[c];
        const float A = sc * rsqrtf(varY + 1e-5f);
        AB[stream * 128 + c] = A;
        AB[stream * 128 + 64 + c] = bi - meanY * A;
    }
}

// ---------- K6: final elementwise, ODD channels only (even written by combine) ----------
__global__ __launch_bounds__(256) void finalize(
    const bf16t* __restrict__ s1, const bf16t* __restrict__ s2,
    const float* __restrict__ x1, const float* __restrict__ x2,
    const float* __restrict__ gates, const float* __restrict__ AB,
    float* __restrict__ out)
{
    const size_t tid = (size_t)blockIdx.x * 256 + threadIdx.x;
    const size_t u = tid * 4;                 // 0 .. 2^22-1 (odd-c element space)
    const int b = (int)(u >> 21);
    const int c = 2 * (int)((u >> 16) & 31) + 1;
    const size_t px = u & 65535u;
    const size_t idx = ((size_t)b << 22) + ((size_t)c << 16) + px;

    const float g1 = gates[b * 64 + c], g2 = gates[128 + b * 64 + c];
    const float A1 = AB[c], B1 = AB[64 + c], A2 = AB[128 + c], B2 = AB[192 + c];

    const uint2 su1 = *(const uint2*)(s1 + idx);
    const uint2 su2 = *(const uint2*)(s2 + idx);
    const float4 x1v = *(const float4*)(x1 + idx);
    const float4 x2v = *(const float4*)(x2 + idx);
    float s1f[4] = {bflo(su1.x), bfhi(su1.x), bflo(su1.y), bfhi(su1.y)};
    float s2f[4] = {bflo(su2.x), bfhi(su2.x), bflo(su2.y), bfhi(su2.y)};
    float xa[4] = {x1v.x, x1v.y, x1v.z, x1v.w};
    float xb[4] = {x2v.x, x2v.y, x2v.z, x2v.w};
    float o1[4], o2[4];
#pragma unroll
    for (int j = 0; j < 4; j++) {
        const float y1 = g1 * s1f[j] + xa[j];
        const float y2 = g2 * s2f[j] + xb[j];
        o1[j] = fmaxf(A1 * y1 + B1, 0.f);
        o2[j] = fmaxf(A2 * y2 + B2, 0.f);
    }
    *(float4*)(out + idx) = make_float4(o1[0], o1[1], o1[2], o1[3]);
    *(float4*)(out + 8388608 + idx) = make_float4(o2[0], o2[1], o2[2], o2[3]);
}

// ---------- host ----------
extern "C" void kernel_launch(void* const* d_in, const int* in_sizes, int n_in,
                              void* d_out, int out_size, void* d_ws, size_t ws_size,
                              hipStream_t stream) {
    (void)in_sizes; (void)n_in; (void)out_size; (void)ws_size;
    const float* x1 = (const float*)d_in[0];
    const float* x2 = (const float*)d_in[1];
    const float* wq1 = (const float*)d_in[2];  const float* bq1 = (const float*)d_in[3];
    const float* wq2 = (const float*)d_in[4];  const float* bq2 = (const float*)d_in[5];
    const float* wk1 = (const float*)d_in[6];  const float* bk1 = (const float*)d_in[7];
    const float* wk2 = (const float*)d_in[8];  const float* bk2 = (const float*)d_in[9];
    const float* wv1 = (const float*)d_in[10]; const float* bv1 = (const float*)d_in[11];
    const float* wv2 = (const float*)d_in[12]; const float* bv2 = (const float*)d_in[13];
    const float* gamma1 = (const float*)d_in[14];
    const float* gamma2 = (const float*)d_in[15];
    const float* sc1_w1 = (const float*)d_in[16]; const float* sc1_b1 = (const float*)d_in[17];
    const float* sc1_w2 = (const float*)d_in[18]; const float* sc1_b2 = (const float*)d_in[19];
    const float* sc2_w1 = (const float*)d_in[20]; const float* sc2_b1 = (const float*)d_in[21];
    const float* sc2_w2 = (const float*)d_in[22]; const float* sc2_b2 = (const float*)d_in[23];
    const float* bn1_scale = (const float*)d_in[24]; const float* bn1_bias = (const float*)d_in[25];
    const float* bn2_scale = (const float*)d_in[26]; const float* bn2_bias = (const float*)d_in[27];

    char* p = (char*)d_ws;
    const size_t SZ_QK = 2097152;   // bf16 (B,8,H,W)
    const size_t SZ_V = 16777216;   // bf16 (B,64,H,W)
    const size_t SZ_ST = 524288;    // fp32 (B,H,W)

    bf16t* q1 = (bf16t*)(p + 0 * SZ_QK);
    bf16t* k1 = (bf16t*)(p + 1 * SZ_QK);
    bf16t* q2 = (bf16t*)(p + 2 * SZ_QK);
    bf16t* k2 = (bf16t*)(p + 3 * SZ_QK);
    bf16t* v1 = (bf16t*)(p + 4 * SZ_QK);
    bf16t* v2 = (bf16t*)(p + 4 * SZ_QK + SZ_V);
    size_t off = 4 * SZ_QK + 2 * SZ_V;
    bf16t* q1T = (bf16t*)(p + off + 0 * SZ_QK);
    bf16t* k1T = (bf16t*)(p + off + 1 * SZ_QK);
    bf16t* q2T = (bf16t*)(p + off + 2 * SZ_QK);
    bf16t* k2T = (bf16t*)(p + off + 3 * SZ_QK);
    bf16t* v1T = (bf16t*)(p + off + 4 * SZ_QK);
    bf16t* v2T = (bf16t*)(p + off + 4 * SZ_QK + SZ_V);
    off += 4 * SZ_QK + 2 * SZ_V;
    bf16t* oH1T = (bf16t*)(p + off); off += SZ_V;
    bf16t* oH2T = (bf16t*)(p + off); off += SZ_V;
    bf16t* oW1 = (bf16t*)(p + off); off += SZ_V;
    bf16t* oW2 = (bf16t*)(p + off); off += SZ_V;
    float* sH1 = (float*)(p + off); off += SZ_ST;   // row-frame (scattered by column pass)
    float* sH2 = (float*)(p + off); off += SZ_ST;
    float* sW1 = (float*)(p + off); off += SZ_ST;
    float* sW2 = (float*)(p + off); off += SZ_ST;
    float* accum = (float*)(p + off);                  // 1280 f32
    unsigned* accmax = (unsigned*)(p + off + 5120);    // 256 u32
    float* gates = (float*)(p + off + 6144);
    float* AB = (float*)(p + off + 7168);

    // overlays: v1T/v2T dead after rowcc -> reuse as s1/s2 (oH1T/oH2T must
    // stay live: combine reads them in T-frame directly, no output transpose)
    bf16t* s1 = v1T;
    bf16t* s2 = v2T;

    // K1: MFMA convs (+ accum zeroing in block 0)
    ConvArgs CA;
    CA.x[0] = x1; CA.x[1] = x2;
    CA.wq[0] = wq1; CA.wq[1] = wq2; CA.bq[0] = bq1; CA.bq[1] = bq2;
    CA.wk[0] = wk1; CA.wk[1] = wk2; CA.bk[0] = bk1; CA.bk[1] = bk2;
    CA.wv[0] = wv1; CA.wv[1] = wv2; CA.bv[0] = bv1; CA.bv[1] = bv2;
    CA.q[0] = q1; CA.q[1] = q2; CA.k[0] = k1; CA.k[1] = k2;
    CA.v[0] = v1; CA.v[1] = v2;
    CA.zeroR = (unsigned*)accum;
    conv_qkv<<<dim3(256, 1, 4), 256, 0, stream>>>(CA);

    // K2: input transposes in one dispatch (q1..k2 = 64 slices, v1,v2 = 256)
    transpose16<<<dim3(4, 4, 320), 256, 0, stream>>>(q1, q1T);

    // K3: fused criss-cross
    RowccArgs RA;
    RA.q[0] = q2T; RA.k[0] = k1T; RA.v[0] = v1T; RA.o[0] = oH1T; RA.so[0] = sH1;
    RA.q[1] = q1T; RA.k[1] = k2T; RA.v[1] = v2T; RA.o[1] = oH2T; RA.so[1] = sH2;
    RA.q[2] = q2;  RA.k[2] = k1;  RA.v[2] = v1;  RA.o[2] = oW1;  RA.so[2] = sW1;
    RA.q[3] = q1;  RA.k[3] = k2;  RA.v[3] = v2;  RA.o[3] = oW2;  RA.so[3] = sW2;
    rowcc_mfma<<<dim3(256, 2, 4), 256, 0, stream>>>(RA);

    // K4: combine (wide lanes: 16h x 256w blocks, grid (16,64,2) = 2048 blocks)
    combine_reduce<<<dim3(16, 64, 2), 256, 0, stream>>>(
        oH1T, oW1, oH2T, oW2, sH1, sW1, sH2, sW2, x1, x2, gamma1, gamma2,
        s1, s2, (float*)d_out, (float*)d_out + 8388608, accum, accmax);

    gates_bn<<<1, 256, 0, stream>>>(accum, accmax,
                                    sc1_w1, sc1_b1, sc1_w2, sc1_b2,
                                    sc2_w1, sc2_b1, sc2_w2, sc2_b2,
                                    bn1_scale, bn1_bias, bn2_scale, bn2_bias,
                                    gates, AB);

    // K6: odd channels only (half the former grid)
    finalize<<<4096, 256, 0, stream>>>(s1, s2, x1, x2, gates, AB, (float*)d_out);
}

// Round 18
// 298.396 us; speedup vs baseline: 1.0091x; 1.0091x over previous
//
#include <hip/hip_runtime.h>
#include <hip/hip_bf16.h>
#include <cstdint>
#include <cstddef>

typedef unsigned short bf16t;
typedef __attribute__((ext_vector_type(8))) short bf16x8;  // 8 bf16 (4 VGPRs)
typedef __attribute__((ext_vector_type(4))) float f32x4;   // MFMA C/D

// ---------- helpers ----------
__device__ __forceinline__ unsigned short f2bf(float f) {
    unsigned u = __float_as_uint(f);
    u += 0x7fffu + ((u >> 16) & 1u);   // RNE
    return (unsigned short)(u >> 16);
}
__device__ __forceinline__ float bf2f(unsigned short h) {
    return __uint_as_float(((unsigned)h) << 16);
}
__device__ __forceinline__ float bflo(unsigned u) { return __uint_as_float(u << 16); }
__device__ __forceinline__ float bfhi(unsigned u) { return __uint_as_float(u & 0xffff0000u); }
// packed f32x2 -> bf16x2 via v_cvt_pk_bf16_f32
__device__ __forceinline__ unsigned pk2(float a, float b) {
    __hip_bfloat162 h = __float22bfloat162_rn(make_float2(a, b));
    return *(unsigned*)&h;
}
__device__ __forceinline__ bf16x8 mk8(unsigned a, unsigned b, unsigned c, unsigned d) {
    union { uint4 u; bf16x8 v; } cv; cv.u = make_uint4(a, b, c, d); return cv.v;
}
// native 2^x (v_exp_f32, no pre-multiply) — Q is pre-scaled by log2e in conv
__device__ __forceinline__ float fexp2(float x) {
#if __has_builtin(__builtin_amdgcn_exp2f)
    return __builtin_amdgcn_exp2f(x);
#else
    return exp2f(x);
#endif
}

// order-preserving float<->uint encoding for atomicMax
__device__ __forceinline__ unsigned fenc(float f) {
    unsigned u = __float_as_uint(f);
    return (u & 0x80000000u) ? ~u : (u | 0x80000000u);
}
__device__ __forceinline__ float fdec(unsigned u) {
    return __uint_as_float((u & 0x80000000u) ? (u ^ 0x80000000u) : ~u);
}

#define HW 65536
#define LOG2E 1.44269504088896f

// ---------- K1: MFMA 1x1 conv: Out[80,HW] = W[80,64] * X[64,HW], X/W cast bf16 ----------
// Q rows (o<8) are pre-scaled by log2e so rowcc can use raw v_exp_f32 (2^x).
struct ConvArgs {
    const float* x[2];
    const float* wq[2]; const float* bq[2];
    const float* wk[2]; const float* bk[2];
    const float* wv[2]; const float* bv[2];
    bf16t* q[2]; bf16t* k[2]; bf16t* v[2];
    unsigned* zeroR;    // 1536 u32: accum (1280 f32) + accmax (256 u32)
};

__global__ __launch_bounds__(256) void conv_qkv(ConvArgs A)
{
    __shared__ __align__(16) bf16t Xlds[256 * 68];   // [px][ch], stride 68

    const int t = threadIdx.x;
    const int z = blockIdx.z;
    const int s = z >> 1, b = z & 1;
    if (z == 0 && blockIdx.x == 0) {
#pragma unroll
        for (int i = 0; i < 6; i++) A.zeroR[t + i * 256] = 0u;
    }
    const int lane = t & 63, wv = t >> 6, quad = lane >> 4, l16 = lane & 15;
    const int px0 = blockIdx.x * 256;

    // --- load X column (64 ch) for px = px0 + t; pack bf16; stage transposed ---
    const float* xp = A.x[s] + (size_t)b * 64 * HW + px0 + t;
    {
        unsigned xw[32];
#pragma unroll
        for (int c = 0; c < 32; c++)
            xw[c] = pk2(xp[(size_t)(2 * c) * HW], xp[(size_t)(2 * c + 1) * HW]);
#pragma unroll
        for (int g = 0; g < 16; g++)
            *(uint2*)&Xlds[t * 68 + g * 4] = make_uint2(xw[2 * g], xw[2 * g + 1]);
    }

    // --- B-frags (W) + bias + output row pointers: o = ot*16 + l16 ---
    bf16x8 bfr[5][2];
    float bo[5];
    bf16t* obase[5];
#pragma unroll
    for (int ot = 0; ot < 5; ot++) {
        const int o = ot * 16 + l16;
        const float* wrow;
        float qs = 1.0f;
        if (o < 8)       { wrow = A.wq[s] + o * 64;        bo[ot] = A.bq[s][o] * LOG2E; qs = LOG2E;
                           obase[ot] = A.q[s] + (size_t)(b * 8 + o) * HW; }
        else if (o < 16) { wrow = A.wk[s] + (o - 8) * 64;  bo[ot] = A.bk[s][o - 8];
                           obase[ot] = A.k[s] + (size_t)(b * 8 + o - 8) * HW; }
        else             { wrow = A.wv[s] + (o - 16) * 64; bo[ot] = A.bv[s][o - 16];
                           obase[ot] = A.v[s] + (size_t)(b * 64 + o - 16) * HW; }
#pragma unroll
        for (int ks = 0; ks < 2; ks++) {
            const float* wp = wrow + ks * 32 + quad * 8;
            bfr[ot][ks] = mk8(pk2(wp[0] * qs, wp[1] * qs), pk2(wp[2] * qs, wp[3] * qs),
                              pk2(wp[4] * qs, wp[5] * qs), pk2(wp[6] * qs, wp[7] * qs));
        }
    }

    __syncthreads();

    // --- A-frags (X^T): wave's px band = wv*64 .. +63, 4 m-tiles ---
    bf16x8 afr[4][2];
#pragma unroll
    for (int i = 0; i < 4; i++)
#pragma unroll
        for (int ks = 0; ks < 2; ks++) {
            const int base = (wv * 64 + i * 16 + l16) * 68 + ks * 32 + quad * 8;
            const uint2 lo = *(const uint2*)&Xlds[base];
            const uint2 hi = *(const uint2*)&Xlds[base + 4];
            afr[i][ks] = mk8(lo.x, lo.y, hi.x, hi.y);
        }

    const f32x4 z4 = {0.f, 0.f, 0.f, 0.f};
    f32x4 acc[4][5];
#pragma unroll
    for (int i = 0; i < 4; i++)
#pragma unroll
        for (int ot = 0; ot < 5; ot++) acc[i][ot] = z4;

#pragma unroll
    for (int ks = 0; ks < 2; ks++)
#pragma unroll
        for (int i = 0; i < 4; i++)
#pragma unroll
            for (int ot = 0; ot < 5; ot++)
                acc[i][ot] = __builtin_amdgcn_mfma_f32_16x16x32_bf16(afr[i][ks], bfr[ot][ks], acc[i][ot], 0, 0, 0);

    // --- epilogue: C rows = px (quad*4+r), cols = o (l16); direct 8B stores ---
#pragma unroll
    for (int i = 0; i < 4; i++) {
        const int px = px0 + wv * 64 + i * 16 + quad * 4;
#pragma unroll
        for (int ot = 0; ot < 5; ot++) {
            uint2 u;
            u.x = pk2(acc[i][ot][0] + bo[ot], acc[i][ot][1] + bo[ot]);
            u.y = pk2(acc[i][ot][2] + bo[ot], acc[i][ot][3] + bo[ot]);
            *(uint2*)&obase[ot][px] = u;
        }
    }
}

// ---------- bf16 transpose, widened: uint (2 elems) per lane both directions ----------
__global__ __launch_bounds__(256) void transpose16(const bf16t* __restrict__ in, bf16t* __restrict__ out)
{
    __shared__ unsigned tile[64][33];   // [row][col-pair]: lo16 = col 2c, hi16 = col 2c+1
    const size_t zo = (size_t)blockIdx.z * HW;
    const int i0 = blockIdx.y * 64, j0 = blockIdx.x * 64;
    const int cp = threadIdx.x & 31;       // col-pair 0..31
    const int r8 = threadIdx.x >> 5;       // 0..7
#pragma unroll
    for (int rr = 0; rr < 8; rr++) {
        const int row = rr * 8 + r8;
        tile[row][cp] = *(const unsigned*)&in[zo + (size_t)(i0 + row) * 256 + j0 + cp * 2];
    }
    __syncthreads();
    const int ip = threadIdx.x & 31;       // output i-pair
    const int j8 = threadIdx.x >> 5;
#pragma unroll
    for (int jj = 0; jj < 8; jj++) {
        const int j = jj * 8 + j8;
        const unsigned a = tile[2 * ip][j >> 1];
        const unsigned b = tile[2 * ip + 1][j >> 1];
        const unsigned lo = (j & 1) ? (a >> 16) : (a & 0xffffu);
        const unsigned hi = (j & 1) ? (b >> 16) : (b & 0xffffu);
        *(unsigned*)&out[zo + (size_t)(j0 + j) * 256 + i0 + ip * 2] = lo | (hi << 16);
    }
}

// ---------- K2: criss-cross rows (verified r13: 47.9 us) ----------
struct RowccArgs {
    const bf16t* q[4]; const bf16t* k[4]; const bf16t* v[4];
    bf16t* o[4]; float* so[4];
};

__global__ __launch_bounds__(256, 3) void rowcc_mfma(RowccArgs P)
{
    __shared__ __align__(16) bf16t vs[64 * 264];     // V [c][j]; epilogue overlays
    __shared__ __align__(16) bf16t klds[256 * 8];    // K transposed [j][ch]

    const int t = threadIdx.x;
    const int r = blockIdx.x, b = blockIdx.y, z = blockIdx.z;
    const bool mask = (z < 2);
    const int lane = t & 63, wv = t >> 6, quad = lane >> 4, l16 = lane & 15;
    const int wband = wv * 64;
    const int jperm = 8 * (l16 >> 2) + (l16 & 3);   // score-row m=l16 -> j offset

    const bf16t* qp = P.q[z];
    const bf16t* kp = P.k[z];
    const bf16t* vp = P.v[z];
    const size_t rowb = (size_t)b * 8 * HW + (size_t)r * 256;

    // --- stage V as [c][j] (row stride 264) ---
    const size_t vb = (size_t)b * 64 * HW + (size_t)r * 256;
#pragma unroll
    for (int i = 0; i < 8; i++) {
        const int qd = i * 256 + t;
        const int c = qd >> 5, jc = (qd & 31) * 8;
        *(uint4*)&vs[c * 264 + jc] = *(const uint4*)&vp[vb + (size_t)c * HW + jc];
    }

    // --- stage K transposed: thread t handles j=t (8 coalesced ch loads + 1 b128 write) ---
    {
        bf16t kv[8];
#pragma unroll
        for (int ch = 0; ch < 8; ch++)
            kv[ch] = kp[rowb + (size_t)ch * HW + t];
        *(uint4*)&klds[t * 8] = *(const uint4*)kv;
    }

    // --- Q B-frags from global (quad0 lanes only; quads 1-3 are K-zero-pad) ---
    const bf16x8 zfr = {0, 0, 0, 0, 0, 0, 0, 0};
    bf16x8 qfr[4] = {zfr, zfr, zfr, zfr};
    if (quad == 0) {
#pragma unroll
        for (int wt = 0; wt < 4; wt++) {
            const int w_g = wband + wt * 16 + l16;
#pragma unroll
            for (int ch = 0; ch < 8; ch++)
                qfr[wt][ch] = (short)qp[rowb + (size_t)ch * HW + w_g];
        }
    }

    const f32x4 z4 = {0.f, 0.f, 0.f, 0.f};
    f32x4 acc[4][4];
#pragma unroll
    for (int i = 0; i < 4; i++)
#pragma unroll
        for (int j = 0; j < 4; j++) acc[i][j] = z4;
    float s_t[4] = {0.f, 0.f, 0.f, 0.f};

    __syncthreads();

    // K A-frag prefetch for jt=0, from LDS
    bf16x8 kcur[2] = {zfr, zfr};
    if (quad == 0) {
#pragma unroll
        for (int jtile = 0; jtile < 2; jtile++)
            kcur[jtile] = *(const bf16x8*)&klds[(jtile * 4 + jperm) * 8];
    }

    for (int jt = 0; jt < 8; jt++) {
        const int j0 = jt * 32;

        // V B-frags for this jt (independent of scores; issue early)
        bf16x8 bfr[4];
#pragma unroll
        for (int ct = 0; ct < 4; ct++)
            bfr[ct] = *(const bf16x8*)&vs[(ct * 16 + l16) * 264 + j0 + quad * 8];

        // prefetch next jt's K frags from LDS (cheap, hidden under MFMA/exp)
        bf16x8 knext[2] = {zfr, zfr};
        if (jt < 7 && quad == 0) {
            const int jn = (jt + 1) * 32;
#pragma unroll
            for (int jtile = 0; jtile < 2; jtile++)
                knext[jtile] = *(const bf16x8*)&klds[(jn + jtile * 4 + jperm) * 8];
        }

        const bool dodiag = mask && ((jt >> 1) == wv);

#pragma unroll
        for (int wt = 0; wt < 4; wt++) {
            f32x4 e0 = __builtin_amdgcn_mfma_f32_16x16x32_bf16(kcur[0], qfr[wt], z4, 0, 0, 0);
            f32x4 e1 = __builtin_amdgcn_mfma_f32_16x16x32_bf16(kcur[1], qfr[wt], z4, 0, 0, 0);

            if (dodiag) {
                const int w_g = wband + wt * 16 + l16;
                const int jb = j0 + 8 * quad;
#pragma unroll
                for (int rr = 0; rr < 4; rr++) {
                    if (jb + rr == w_g)     e0[rr] = -3.0e38f;
                    if (jb + 4 + rr == w_g) e1[rr] = -3.0e38f;
                }
            }

            // p = 2^e (Q pre-scaled by log2e); accumulate denominator;
            // pack PV A-frag in registers
            float p[8];
#pragma unroll
            for (int rr = 0; rr < 4; rr++) {
                p[rr]     = fexp2(e0[rr]);
                p[4 + rr] = fexp2(e1[rr]);
            }
            s_t[wt] += ((p[0] + p[1]) + (p[2] + p[3])) + ((p[4] + p[5]) + (p[6] + p[7]));
            const bf16x8 pa = mk8(pk2(p[0], p[1]), pk2(p[2], p[3]),
                                  pk2(p[4], p[5]), pk2(p[6], p[7]));

            // PV: A = P (w x j), B = V (j x c)
#pragma unroll
            for (int ct = 0; ct < 4; ct++)
                acc[wt][ct] = __builtin_amdgcn_mfma_f32_16x16x32_bf16(pa, bfr[ct], acc[wt][ct], 0, 0, 0);
        }

        kcur[0] = knext[0]; kcur[1] = knext[1];
    }

    // denominator: reduce across quads (each quad holds a disjoint j-subset)
#pragma unroll
    for (int wt = 0; wt < 4; wt++) {
        float s = s_t[wt];
        s += __shfl_xor(s, 16, 64);
        s += __shfl_xor(s, 32, 64);
        s_t[wt] = s;
    }
    if (quad == 0) {
#pragma unroll
        for (int wt = 0; wt < 4; wt++) {
            const int w_g = wband + wt * 16 + l16;
            if (mask)  // column pass: pixel (h=w_g, w=r) in row-frame
                P.so[z][(size_t)b * HW + w_g * 256 + r] = s_t[wt];
            else
                P.so[z][(size_t)b * HW + r * 256 + w_g] = s_t[wt];
        }
    }

    // epilogue: C-layout -> LDS [c][w] -> coalesced global [c][w]
    __syncthreads();
    bf16t* o_lds = vs;
#pragma unroll
    for (int wt = 0; wt < 4; wt++) {
        const int w0 = wband + wt * 16 + quad * 4;
#pragma unroll
        for (int ct = 0; ct < 4; ct++) {
            const int c = ct * 16 + l16;
            uint2 u;
            u.x = pk2(acc[wt][ct][0], acc[wt][ct][1]);
            u.y = pk2(acc[wt][ct][2], acc[wt][ct][3]);
            *(uint2*)&o_lds[c * 264 + w0] = u;
        }
    }
    __syncthreads();
    bf16t* ob = P.o[z] + (size_t)b * 64 * HW + (size_t)r * 256;
#pragma unroll
    for (int i = 0; i < 8; i++) {
        const int qd = i * 256 + t;
        const int c = qd >> 5, w8 = (qd & 31) * 8;
        *(uint4*)&ob[(size_t)c * HW + w8] = *(const uint4*)&o_lds[c * 264 + w8];
    }
}

// ---------- K4: combine, 32h x 128w blocks: every stream gets >=64B segments ----------
// oHT stage: one FULL 64B cache line per lane (thread t<128: oH1T row w0+t,
// h0..h0+31; threads 128-255: oH2T) -> zero over-fetch (r16's 32B@512B-stride
// staging over-fetched 2x: FETCH 116MB vs 67MB). Compute: lane owns 4 w;
// x/out float4 (512B/half-wave), oW/s1/s2 uint2 (256B segments).
// oth stride 130 (260B): half-waves land on even/odd banks = conflict-free.
// Grid (16,64,2) = 2048 blocks (round-6 lesson: keep parallelism).
__global__ __launch_bounds__(256) void combine_reduce(
    const bf16t* __restrict__ oH1T, const bf16t* __restrict__ oW1,
    const bf16t* __restrict__ oH2T, const bf16t* __restrict__ oW2,
    const float* __restrict__ sH1, const float* __restrict__ sW1,
    const float* __restrict__ sH2, const float* __restrict__ sW2,
    const float* __restrict__ x1, const float* __restrict__ x2,
    const float* __restrict__ gamma1, const float* __restrict__ gamma2,
    bf16t* __restrict__ s1, bf16t* __restrict__ s2,
    float* __restrict__ out1, float* __restrict__ out2,
    float* __restrict__ accum, unsigned* __restrict__ accmax)
{
    __shared__ bf16t oth1[32][130];   // [h_local][w_local], stride 260B
    __shared__ bf16t oth2[32][130];

    const int t = threadIdx.x;
    const int wblk = blockIdx.x & 1, hblk = blockIdx.x >> 1;   // 2 wblk x 8 hblk
    const int c = blockIdx.y, b = blockIdx.z;
    const float g1v = gamma1[0], g2v = gamma2[0];
    const size_t cb = ((size_t)(b * 64 + c)) * HW;
    const size_t pb = (size_t)b * HW;
    const bool codd = (c & 1) != 0;
    const int h0 = hblk * 32;
    const int w0 = wblk * 128;

    // --- stage: thread t<128 -> oH1T row w=w0+t (64B = h0..h0+31); t>=128 -> oH2T ---
    {
        const int wl = t & 127;
        const bf16t* src = (t < 128) ? oH1T : oH2T;
        bf16t* dst = (t < 128) ? &oth1[0][0] : &oth2[0][0];
        const size_t g = cb + (size_t)(w0 + wl) * 256 + h0;
        const uint4 u0 = *(const uint4*)&src[g];
        const uint4 u1 = *(const uint4*)&src[g + 8];
        const uint4 u2 = *(const uint4*)&src[g + 16];
        const uint4 u3 = *(const uint4*)&src[g + 24];
        const unsigned uu[16] = {u0.x, u0.y, u0.z, u0.w, u1.x, u1.y, u1.z, u1.w,
                                 u2.x, u2.y, u2.z, u2.w, u3.x, u3.y, u3.z, u3.w};
#pragma unroll
        for (int i = 0; i < 16; i++) {
            dst[(2 * i + 0) * 130 + wl] = (bf16t)(uu[i] & 0xffffu);
            dst[(2 * i + 1) * 130 + wl] = (bf16t)(uu[i] >> 16);
        }
    }
    __syncthreads();

    const int l = t & 63, wv = t >> 6;
    const int wloc = (l & 31) * 4;        // lane's 4 w columns (local)
    const int w4 = w0 + wloc;
    const int hsub = l >> 5;              // 0 or 1

    float pS1 = 0, pSS1 = 0, pSX1 = 0, pX1 = 0, pXX1 = 0, pM1 = -3e38f;
    float pS2 = 0, pSS2 = 0, pSX2 = 0, pX2 = 0, pXX2 = 0, pM2 = -3e38f;

    // --- process: wave wv, iter k: h_local = wv*8 + k*2 + hsub (covers 32 h) ---
#pragma unroll
    for (int k = 0; k < 4; k++) {
        const int hl = wv * 8 + k * 2 + hsub;
        const int pidx = (h0 + hl) * 256 + w4;
        const float4 sh1 = *(const float4*)&sH1[pb + pidx];
        const float4 sw1 = *(const float4*)&sW1[pb + pidx];
        const float4 sh2 = *(const float4*)&sH2[pb + pidx];
        const float4 sw2 = *(const float4*)&sW2[pb + pidx];
        const uint2 ow1 = *(const uint2*)&oW1[cb + pidx];
        const uint2 ow2 = *(const uint2*)&oW2[cb + pidx];
        const uint2 oh1 = *(const uint2*)&oth1[hl][wloc];
        const uint2 oh2 = *(const uint2*)&oth2[hl][wloc];
        const float4 x1v = *(const float4*)&x1[cb + pidx];
        const float4 x2v = *(const float4*)&x2[cb + pidx];

        const float i1[4] = {1.f / (sh1.x + sw1.x), 1.f / (sh1.y + sw1.y),
                             1.f / (sh1.z + sw1.z), 1.f / (sh1.w + sw1.w)};
        const float i2[4] = {1.f / (sh2.x + sw2.x), 1.f / (sh2.y + sw2.y),
                             1.f / (sh2.z + sw2.z), 1.f / (sh2.w + sw2.w)};
        const float a1v[4] = {(bflo(oh1.x) + bflo(ow1.x)) * i1[0], (bfhi(oh1.x) + bfhi(ow1.x)) * i1[1],
                              (bflo(oh1.y) + bflo(ow1.y)) * i1[2], (bfhi(oh1.y) + bfhi(ow1.y)) * i1[3]};
        const float a2v[4] = {(bflo(oh2.x) + bflo(ow2.x)) * i2[0], (bfhi(oh2.x) + bfhi(ow2.x)) * i2[1],
                              (bflo(oh2.y) + bflo(ow2.y)) * i2[2], (bfhi(oh2.y) + bfhi(ow2.y)) * i2[3]};
        const float xa[4] = {x1v.x, x1v.y, x1v.z, x1v.w};
        const float xb[4] = {x2v.x, x2v.y, x2v.z, x2v.w};
        float s1v[4], s2v[4];
#pragma unroll
        for (int j = 0; j < 4; j++) {
            s1v[j] = g2v * a2v[j] + xb[j] + xa[j];
            s2v[j] = g1v * a1v[j] + xa[j] + xb[j];
            pS1 += s1v[j]; pSS1 += s1v[j] * s1v[j]; pSX1 += s1v[j] * xa[j];
            pX1 += xa[j];  pXX1 += xa[j] * xa[j];   pM1 = fmaxf(pM1, s1v[j]);
            pS2 += s2v[j]; pSS2 += s2v[j] * s2v[j]; pSX2 += s2v[j] * xb[j];
            pX2 += xb[j];  pXX2 += xb[j] * xb[j];   pM2 = fmaxf(pM2, s2v[j]);
        }
        if (codd) {
            uint2 u1, u2;
            u1.x = pk2(s1v[0], s1v[1]); u1.y = pk2(s1v[2], s1v[3]);
            u2.x = pk2(s2v[0], s2v[1]); u2.y = pk2(s2v[2], s2v[3]);
            *(uint2*)&s1[cb + pidx] = u1;
            *(uint2*)&s2[cb + pidx] = u2;
        } else {
            *(float4*)&out1[cb + pidx] = x1v;   // even c: passthrough, final value
            *(float4*)&out2[cb + pidx] = x2v;
        }
    }

    __shared__ float wred[12][4];
    float vals[12] = {pS1, pSS1, pSX1, pX1, pXX1, pM1, pS2, pSS2, pSX2, pX2, pXX2, pM2};
#pragma unroll
    for (int iv = 0; iv < 12; iv++) {
        float v = vals[iv];
        const bool isMax = (iv == 5 || iv == 11);
#pragma unroll
        for (int off = 32; off > 0; off >>= 1) {
            const float o = __shfl_down(v, off, 64);
            v = isMax ? fmaxf(v, o) : (v + o);
        }
        if (l == 0) wred[iv][wv] = v;
    }
    __syncthreads();
    if (t < 12) {
        const bool isMax = (t == 5 || t == 11);
        float v = wred[t][0];
        for (int i = 1; i < 4; i++) v = isMax ? fmaxf(v, wred[t][i]) : (v + wred[t][i]);
        const int stream = (t >= 6) ? 1 : 0;
        const int kk = t - stream * 6;
        if (kk == 5) atomicMax(&accmax[(stream * 2 + b) * 64 + c], fenc(v));
        else atomicAdd(&accum[((stream * 2 + b) * 64 + c) * 5 + kk], v);
    }
}

// ---------- K5: gates (shareca MLP) + analytic BN coefficients ----------
__global__ __launch_bounds__(256) void gates_bn(
    const float* __restrict__ accum, const unsigned* __restrict__ accmax,
    const float* __restrict__ sc1_w1, const float* __restrict__ sc1_b1,
    const float* __restrict__ sc1_w2, const float* __restrict__ sc1_b2,
    const float* __restrict__ sc2_w1, const float* __restrict__ sc2_b1,
    const float* __restrict__ sc2_w2, const float* __restrict__ sc2_b2,
    const float* __restrict__ bn1_scale, const float* __restrict__ bn1_bias,
    const float* __restrict__ bn2_scale, const float* __restrict__ bn2_bias,
    float* __restrict__ gates, float* __restrict__ AB)
{
    const int t = threadIdx.x;
    const int stream = t >> 7, b = (t >> 6) & 1, c = t & 63;
    __shared__ float meanS[256], maxS[256], e1S[256], e2S[256];

    const float S = accum[t * 5 + 0], SS = accum[t * 5 + 1], SX = accum[t * 5 + 2];
    const float X = accum[t * 5 + 3], XX = accum[t * 5 + 4];
    meanS[t] = S * (1.f / 65536.f);
    maxS[t] = fdec(accmax[t]);
    __syncthreads();

    const float* w1 = stream ? sc2_w1 : sc1_w1;
    const float* b1 = stream ? sc2_b1 : sc1_b1;
    const float* w2 = stream ? sc2_w2 : sc1_w2;
    const float* b2 = stream ? sc2_b2 : sc1_b2;
    float om = b2[c], ox = b2[c];
    const int base = stream * 128 + b * 64;
#pragma unroll
    for (int r = 0; r < 4; r++) {
        float hm = b1[r], hx = b1[r];
        for (int cc = 0; cc < 64; cc++) {
            hm += w1[r * 64 + cc] * meanS[base + cc];
            hx += w1[r * 64 + cc] * maxS[base + cc];
        }
        hm = fmaxf(hm, 0.f); hx = fmaxf(hx, 0.f);
        om += w2[c * 4 + r] * hm;
        ox += w2[c * 4 + r] * hx;
    }
    const float gate = 1.f / (1.f + __expf(-(om + ox)));
    gates[t] = gate;
    e1S[t] = gate * S + X;
    e2S[t] = gate * gate * SS + 2.f * gate * SX + XX;
    __syncthreads();
    if (b == 0) {
        const float sumY = e1S[t] + e1S[t + 64];
        const float sumY2 = e2S[t] + e2S[t + 64];
        const float meanY = sumY * (1.f / 131072.f);
        const float varY = sumY2 * (1.f / 131072.f) - meanY * meanY;
        const float sc = stream ? bn2_scale[c] : bn1_scale[c];
        const float bi = stream ? bn2_bias[c] : bn1_bias[c];
        const float A = sc * rsqrtf(varY + 1e-5f);
        AB[stream * 128 + c] = A;
        AB[stream * 128 + 64 + c] = bi - meanY * A;
    }
}

// ---------- K6: final elementwise, ODD channels only (even written by combine) ----------
__global__ __launch_bounds__(256) void finalize(
    const bf16t* __restrict__ s1, const bf16t* __restrict__ s2,
    const float* __restrict__ x1, const float* __restrict__ x2,
    const float* __restrict__ gates, const float* __restrict__ AB,
    float* __restrict__ out)
{
    const size_t tid = (size_t)blockIdx.x * 256 + threadIdx.x;
    const size_t u = tid * 4;                 // 0 .. 2^22-1 (odd-c element space)
    const int b = (int)(u >> 21);
    const int c = 2 * (int)((u >> 16) & 31) + 1;
    const size_t px = u & 65535u;
    const size_t idx = ((size_t)b << 22) + ((size_t)c << 16) + px;

    const float g1 = gates[b * 64 + c], g2 = gates[128 + b * 64 + c];
    const float A1 = AB[c], B1 = AB[64 + c], A2 = AB[128 + c], B2 = AB[192 + c];

    const uint2 su1 = *(const uint2*)(s1 + idx);
    const uint2 su2 = *(const uint2*)(s2 + idx);
    const float4 x1v = *(const float4*)(x1 + idx);
    const float4 x2v = *(const float4*)(x2 + idx);
    float s1f[4] = {bflo(su1.x), bfhi(su1.x), bflo(su1.y), bfhi(su1.y)};
    float s2f[4] = {bflo(su2.x), bfhi(su2.x), bflo(su2.y), bfhi(su2.y)};
    float xa[4] = {x1v.x, x1v.y, x1v.z, x1v.w};
    float xb[4] = {x2v.x, x2v.y, x2v.z, x2v.w};
    float o1[4], o2[4];
#pragma unroll
    for (int j = 0; j < 4; j++) {
        const float y1 = g1 * s1f[j] + xa[j];
        const float y2 = g2 * s2f[j] + xb[j];
        o1[j] = fmaxf(A1 * y1 + B1, 0.f);
        o2[j] = fmaxf(A2 * y2 + B2, 0.f);
    }
    *(float4*)(out + idx) = make_float4(o1[0], o1[1], o1[2], o1[3]);
    *(float4*)(out + 8388608 + idx) = make_float4(o2[0], o2[1], o2[2], o2[3]);
}

// ---------- host ----------
extern "C" void kernel_launch(void* const* d_in, const int* in_sizes, int n_in,
                              void* d_out, int out_size, void* d_ws, size_t ws_size,
                              hipStream_t stream) {
    (void)in_sizes; (void)n_in; (void)out_size; (void)ws_size;
    const float* x1 = (const float*)d_in[0];
    const float* x2 = (const float*)d_in[1];
    const float* wq1 = (const float*)d_in[2];  const float* bq1 = (const float*)d_in[3];
    const float* wq2 = (const float*)d_in[4];  const float* bq2 = (const float*)d_in[5];
    const float* wk1 = (const float*)d_in[6];  const float* bk1 = (const float*)d_in[7];
    const float* wk2 = (const float*)d_in[8];  const float* bk2 = (const float*)d_in[9];
    const float* wv1 = (const float*)d_in[10]; const float* bv1 = (const float*)d_in[11];
    const float* wv2 = (const float*)d_in[12]; const float* bv2 = (const float*)d_in[13];
    const float* gamma1 = (const float*)d_in[14];
    const float* gamma2 = (const float*)d_in[15];
    const float* sc1_w1 = (const float*)d_in[16]; const float* sc1_b1 = (const float*)d_in[17];
    const float* sc1_w2 = (const float*)d_in[18]; const float* sc1_b2 = (const float*)d_in[19];
    const float* sc2_w1 = (const float*)d_in[20]; const float* sc2_b1 = (const float*)d_in[21];
    const float* sc2_w2 = (const float*)d_in[22]; const float* sc2_b2 = (const float*)d_in[23];
    const float* bn1_scale = (const float*)d_in[24]; const float* bn1_bias = (const float*)d_in[25];
    const float* bn2_scale = (const float*)d_in[26]; const float* bn2_bias = (const float*)d_in[27];

    char* p = (char*)d_ws;
    const size_t SZ_QK = 2097152;   // bf16 (B,8,H,W)
    const size_t SZ_V = 16777216;   // bf16 (B,64,H,W)
    const size_t SZ_ST = 524288;    // fp32 (B,H,W)

    bf16t* q1 = (bf16t*)(p + 0 * SZ_QK);
    bf16t* k1 = (bf16t*)(p + 1 * SZ_QK);
    bf16t* q2 = (bf16t*)(p + 2 * SZ_QK);
    bf16t* k2 = (bf16t*)(p + 3 * SZ_QK);
    bf16t* v1 = (bf16t*)(p + 4 * SZ_QK);
    bf16t* v2 = (bf16t*)(p + 4 * SZ_QK + SZ_V);
    size_t off = 4 * SZ_QK + 2 * SZ_V;
    bf16t* q1T = (bf16t*)(p + off + 0 * SZ_QK);
    bf16t* k1T = (bf16t*)(p + off + 1 * SZ_QK);
    bf16t* q2T = (bf16t*)(p + off + 2 * SZ_QK);
    bf16t* k2T = (bf16t*)(p + off + 3 * SZ_QK);
    bf16t* v1T = (bf16t*)(p + off + 4 * SZ_QK);
    bf16t* v2T = (bf16t*)(p + off + 4 * SZ_QK + SZ_V);
    off += 4 * SZ_QK + 2 * SZ_V;
    bf16t* oH1T = (bf16t*)(p + off); off += SZ_V;
    bf16t* oH2T = (bf16t*)(p + off); off += SZ_V;
    bf16t* oW1 = (bf16t*)(p + off); off += SZ_V;
    bf16t* oW2 = (bf16t*)(p + off); off += SZ_V;
    float* sH1 = (float*)(p + off); off += SZ_ST;   // row-frame (scattered by column pass)
    float* sH2 = (float*)(p + off); off += SZ_ST;
    float* sW1 = (float*)(p + off); off += SZ_ST;
    float* sW2 = (float*)(p + off); off += SZ_ST;
    float* accum = (float*)(p + off);                  // 1280 f32
    unsigned* accmax = (unsigned*)(p + off + 5120);    // 256 u32
    float* gates = (float*)(p + off + 6144);
    float* AB = (float*)(p + off + 7168);

    // overlays: v1T/v2T dead after rowcc -> reuse as s1/s2 (oH1T/oH2T must
    // stay live: combine reads them in T-frame directly, no output transpose)
    bf16t* s1 = v1T;
    bf16t* s2 = v2T;

    // K1: MFMA convs (+ accum zeroing in block 0)
    ConvArgs CA;
    CA.x[0] = x1; CA.x[1] = x2;
    CA.wq[0] = wq1; CA.wq[1] = wq2; CA.bq[0] = bq1; CA.bq[1] = bq2;
    CA.wk[0] = wk1; CA.wk[1] = wk2; CA.bk[0] = bk1; CA.bk[1] = bk2;
    CA.wv[0] = wv1; CA.wv[1] = wv2; CA.bv[0] = bv1; CA.bv[1] = bv2;
    CA.q[0] = q1; CA.q[1] = q2; CA.k[0] = k1; CA.k[1] = k2;
    CA.v[0] = v1; CA.v[1] = v2;
    CA.zeroR = (unsigned*)accum;
    conv_qkv<<<dim3(256, 1, 4), 256, 0, stream>>>(CA);

    // K2: input transposes in one dispatch (q1..k2 = 64 slices, v1,v2 = 256)
    transpose16<<<dim3(4, 4, 320), 256, 0, stream>>>(q1, q1T);

    // K3: fused criss-cross
    RowccArgs RA;
    RA.q[0] = q2T; RA.k[0] = k1T; RA.v[0] = v1T; RA.o[0] = oH1T; RA.so[0] = sH1;
    RA.q[1] = q1T; RA.k[1] = k2T; RA.v[1] = v2T; RA.o[1] = oH2T; RA.so[1] = sH2;
    RA.q[2] = q2;  RA.k[2] = k1;  RA.v[2] = v1;  RA.o[2] = oW1;  RA.so[2] = sW1;
    RA.q[3] = q1;  RA.k[3] = k2;  RA.v[3] = v2;  RA.o[3] = oW2;  RA.so[3] = sW2;
    rowcc_mfma<<<dim3(256, 2, 4), 256, 0, stream>>>(RA);

    // K4: combine (32h x 128w blocks: full-cache-line oHT stage; 2048 blocks)
    combine_reduce<<<dim3(16, 64, 2), 256, 0, stream>>>(
        oH1T, oW1, oH2T, oW2, sH1, sW1, sH2, sW2, x1, x2, gamma1, gamma2,
        s1, s2, (float*)d_out, (float*)d_out + 8388608, accum, accmax);

    gates_bn<<<1, 256, 0, stream>>>(accum, accmax,
                                    sc1_w1, sc1_b1, sc1_w2, sc1_b2,
                                    sc2_w1, sc2_b1, sc2_w2, sc2_b2,
                                    bn1_scale, bn1_bias, bn2_scale, bn2_bias,
                                    gates, AB);

    // K6: odd channels only (half the former grid)
    finalize<<<4096, 256, 0, stream>>>(s1, s2, x1, x2, gates, AB, (float*)d_out);
}